// Round 1
// 109.971 us; speedup vs baseline: 1.0700x; 1.0700x over previous
//
#include <hip/hip_runtime.h>
#include <math.h>

constexpr int BS = 32, NV = 321, PL = 12, DM = 128;
constexpr int KT = 32;  // int(64*0.5) patches masked by time criterion
constexpr int KF = 25;  // int(64*0.4) patches masked by freq criterion
constexpr int VB = 8;       // variables per block (kernel A)
constexpr int NCHUNK = 41;  // 40 full chunks + 1 tail chunk (nv=1)
constexpr int SST = 72;     // score row stride: (72*vv+p)%32 -> <=2-way (free)
constexpr int TOTPV = BS * 64 * NV;      // 657408 patch-vars; 2568*256 exactly
constexpr int MASK_BYTE_OFF = 4096;      // masks live at ws+4096

// map float -> uint such that uint order == float order (total, -0 < +0)
__device__ __forceinline__ unsigned ord(float f) {
  unsigned u = __float_as_uint(f);
  return ((int)u < 0) ? ~u : (u | 0x80000000u);
}

// ---------------------------------------------------------------------------
// Kernel A: per-patch scores + per-(b,v) radix top-k -> 2x u64 keep-masks in ws.
// 512 threads, ONE patch-var per thread (p = t>>3, vv = t&7: lanes sweep vv ->
// 384B contiguous runs). One wave per variable does the ranking.
// Blocks with chunk==NCHUNK compute the prep constants (folded prep kernel):
// ws floats: [0,144) Mt[l][i] (TRANSPOSED: l-major), [144,156) c = b_in@W_out,
//            [156,168) St = tt*colsum(W_out), [168,180) Sf, [180,192) b_out.
// ---------------------------------------------------------------------------
__global__ __launch_bounds__(512, 8) void score_kernel(
    const float* __restrict__ x, const float* __restrict__ W_in,
    const float* __restrict__ b_in, const float* __restrict__ W_out,
    const float* __restrict__ b_out, const float* __restrict__ tt,
    const float* __restrict__ ft, float* __restrict__ ws) {
  const int t = threadIdx.x;
  const int chunk = blockIdx.x;
  const int b = blockIdx.y;

  if (chunk == NCHUNK) {  // ---- folded prep (one block does it) ----
    if (b != 0) return;
    if (t < 144) {
      const int l = t / 12, i = t % 12;  // ws[t] = Mt[l][i] = sum_d Win[i][d]*Wout[d][l]
      const float4* Wi = (const float4*)(W_in + i * DM);
      float s = 0.f;
#pragma unroll 8
      for (int d4 = 0; d4 < 32; ++d4) {
        float4 a = Wi[d4];
        const float* wo = W_out + d4 * 48 + l;
        s += a.x * wo[0] + a.y * wo[12] + a.z * wo[24] + a.w * wo[36];
      }
      ws[t] = s;
    } else if (t < 168) {
      const int l = (t - 144) % 12;
      float cs = 0.f, cb = 0.f;
#pragma unroll 8
      for (int d = 0; d < DM; ++d) {
        float w = W_out[d * 12 + l];
        cs += w;
        cb += b_in[d] * w;
      }
      if (t < 156) {
        ws[144 + l] = cb;
        ws[156 + l] = tt[0] * cs;
      } else {
        ws[168 + l] = ft[0] * cs;
      }
    } else if (t < 180) {
      ws[180 + (t - 168)] = b_out[t - 168];
    }
    return;
  }

  __shared__ float scv[VB * SST];
  __shared__ float sfs[VB * SST];

  const int v0 = chunk * VB;
  const bool full = (chunk < 40);
  const int nv = full ? VB : 1;

  const float* xb = x + ((size_t)(b * 64) * NV + v0) * PL;

  int p, vv;
  bool valid;
  if (full) {
    p = t >> 3;
    vv = t & 7;
    valid = true;
  } else {
    p = t & 63;
    vv = 0;
    valid = (t < 64);
  }

  if (valid) {
    const float4* src = (const float4*)(xb + ((size_t)p * NV + vv) * PL);
    float4 a = src[0], bb = src[1], c = src[2];
    float xv[12];
    xv[0] = a.x;  xv[1] = a.y;  xv[2] = a.z;  xv[3] = a.w;
    xv[4] = bb.x; xv[5] = bb.y; xv[6] = bb.z; xv[7] = bb.w;
    xv[8] = c.x;  xv[9] = c.y;  xv[10] = c.z; xv[11] = c.w;

    // coefficient of variation: std(ddof=1)/(mean+1e-6)
    float s = 0.f;
#pragma unroll
    for (int i = 0; i < 12; ++i) s += xv[i];
    const float m = s * (1.0f / 12.0f);
    float ss = 0.f;
#pragma unroll
    for (int i = 0; i < 12; ++i) {
      float d = xv[i] - m;
      ss += d * d;
    }
    const float cv = sqrtf(ss * (1.0f / 11.0f)) / (m + 1e-6f);

    // mean |rfft12| over 7 bins, even/odd folded exact 30-degree DFT
    const float H = 0.86602540378443864676f;  // sqrt(3)/2
    const float e1 = xv[1] + xv[11], e2 = xv[2] + xv[10], e3 = xv[3] + xv[9],
                e4 = xv[4] + xv[8], e5 = xv[5] + xv[7];
    const float o1 = xv[1] - xv[11], o2 = xv[2] - xv[10], o3 = xv[3] - xv[9],
                o4 = xv[4] - xv[8], o5 = xv[5] - xv[7];
    float mag = fabsf(xv[0] + xv[6] + e1 + e2 + e3 + e4 + e5);  // k=0
    float re = xv[0] - xv[6] + H * (e1 - e5) + 0.5f * (e2 - e4);
    float im = 0.5f * (o1 + o5) + H * (o2 + o4) + o3;
    mag += sqrtf(re * re + im * im);  // k=1
    re = xv[0] + xv[6] + 0.5f * (e1 + e5) - 0.5f * (e2 + e4) - e3;
    im = H * (o1 + o2 - o4 - o5);
    mag += sqrtf(re * re + im * im);  // k=2
    re = xv[0] - xv[6] - e2 + e4;
    im = o1 - o3 + o5;
    mag += sqrtf(re * re + im * im);  // k=3
    re = xv[0] + xv[6] - 0.5f * (e1 + e2 + e4 + e5) + e3;
    im = H * (o1 - o2 + o4 - o5);
    mag += sqrtf(re * re + im * im);  // k=4
    re = xv[0] - xv[6] + H * (e5 - e1) + 0.5f * (e2 - e4);
    im = 0.5f * (o1 + o5) - H * (o2 + o4) + o3;
    mag += sqrtf(re * re + im * im);  // k=5
    re = xv[0] + xv[6] - e1 + e2 - e3 + e4 - e5;
    mag += fabsf(re);  // k=6
    const float fs = mag * (1.0f / 7.0f);

    scv[vv * SST + p] = cv;
    sfs[vv * SST + p] = fs;
  }
  __syncthreads();

  // ---- dual radix top-k: wave wv ranks variable wv, lane = p ----
  const int wv = t >> 6, lane = t & 63;
  if (wv < nv) {  // wave-uniform
    const unsigned ut = ord(scv[wv * SST + lane]);   // rank KT LARGEST cv
    const unsigned uf = ~ord(sfs[wv * SST + lane]);  // rank KF SMALLEST fs
    unsigned tht = 0, thf = 0;
#pragma unroll
    for (int bit = 31; bit >= 0; --bit) {
      const unsigned ct = tht | (1u << bit);
      const unsigned cf = thf | (1u << bit);
      const unsigned long long bt = __ballot(ut >= ct);
      const unsigned long long bf = __ballot(uf >= cf);
      if (__popcll(bt) >= KT) tht = ct;
      if (__popcll(bf) >= KF) thf = cf;
    }
    const unsigned long long pre = (1ull << lane) - 1ull;
    const int gt_t = __popcll(__ballot(ut > tht));
    const int rt = __popcll(__ballot(ut == tht) & pre);
    const bool masked_t = (ut > tht) || ((ut == tht) && (rt < KT - gt_t));
    const int gt_f = __popcll(__ballot(uf > thf));
    const int rf = __popcll(__ballot(uf == thf) & pre);
    const bool masked_f = (uf > thf) || ((uf == thf) && (rf < KF - gt_f));
    const unsigned long long bkt = __ballot(!masked_t);  // keep-bits (time)
    const unsigned long long bkf = __ballot(!masked_f);  // keep-bits (freq)
    if (lane == 0) {
      unsigned long long* mk =
          (unsigned long long*)((char*)ws + MASK_BYTE_OFF);
      const int vidx = b * NV + v0 + wv;
      mk[2 * vidx] = bkt;
      mk[2 * vidx + 1] = bkf;
    }
  }
}

// ---------------------------------------------------------------------------
// Kernel B: barrier-free streaming decode. One thread per patch-var.
// E = c + x . Mt  (Mt rows are contiguous -> wave-uniform SCALAR loads, no LDS)
// out = 0.5*((kt?E:St) + (kf?E:Sf)) + b_out. Reads of x hit L3 (hot from A).
// ---------------------------------------------------------------------------
__global__ __launch_bounds__(256, 8) void decode_kernel(
    const float* __restrict__ x, const float* __restrict__ ws,
    float* __restrict__ out) {
  const int g = blockIdx.x * 256 + threadIdx.x;  // [0, 657408), exact grid
  const unsigned v = (unsigned)g % NV;
  const unsigned bp = (unsigned)g / NV;  // b*64 + p
  const int p = bp & 63;
  const int b = bp >> 6;

  const float4* src = (const float4*)(x + (size_t)g * PL);
  float4 a = src[0], bb = src[1], c = src[2];
  float xv[12];
  xv[0] = a.x;  xv[1] = a.y;  xv[2] = a.z;  xv[3] = a.w;
  xv[4] = bb.x; xv[5] = bb.y; xv[6] = bb.z; xv[7] = bb.w;
  xv[8] = c.x;  xv[9] = c.y;  xv[10] = c.z; xv[11] = c.w;

  const unsigned long long* mk =
      (const unsigned long long*)((const char*)ws + MASK_BYTE_OFF);
  const int vidx = b * NV + (int)v;
  const unsigned long long mT = mk[2 * vidx];
  const unsigned long long mF = mk[2 * vidx + 1];
  const bool kt = (mT >> p) & 1ull;
  const bool kf = (mF >> p) & 1ull;

  float o[12];
#pragma unroll
  for (int l0 = 0; l0 < 12; l0 += 4) {
#pragma unroll
    for (int l = l0; l < l0 + 4; ++l) {
      const float* Ml = ws + l * 12;  // Mt row l: contiguous 48B, uniform
      float e = ws[144 + l];
#pragma unroll
      for (int i = 0; i < 12; ++i) e = fmaf(xv[i], Ml[i], e);
      const float at = kt ? e : ws[156 + l];
      const float af = kf ? e : ws[168 + l];
      o[l] = 0.5f * (at + af) + ws[180 + l];
    }
    if (l0 < 8) __builtin_amdgcn_sched_barrier(0);  // cap SGPR liveness per group
  }

  float* op = out + (size_t)g * PL;
  ((float4*)op)[0] = make_float4(o[0], o[1], o[2], o[3]);
  ((float4*)op)[1] = make_float4(o[4], o[5], o[6], o[7]);
  ((float4*)op)[2] = make_float4(o[8], o[9], o[10], o[11]);
}

extern "C" void kernel_launch(void* const* d_in, const int* in_sizes, int n_in,
                              void* d_out, int out_size, void* d_ws,
                              size_t ws_size, hipStream_t stream) {
  const float* x = (const float*)d_in[0];
  const float* W_in = (const float*)d_in[1];
  const float* b_in = (const float*)d_in[2];
  const float* W_out = (const float*)d_in[3];
  const float* b_out = (const float*)d_in[4];
  const float* tt = (const float*)d_in[5];
  const float* ft = (const float*)d_in[6];
  float* out = (float*)d_out;
  float* ws = (float*)d_ws;  // [0,192) prep floats; +4096B: 32*321*2 u64 masks

  hipLaunchKernelGGL(score_kernel, dim3(NCHUNK + 1, BS), dim3(512), 0, stream,
                     x, W_in, b_in, W_out, b_out, tt, ft, ws);
  hipLaunchKernelGGL(decode_kernel, dim3(TOTPV / 256), dim3(256), 0, stream, x,
                     ws, out);
}